// Round 4
// baseline (963.173 us; speedup 1.0000x reference)
//
#include <hip/hip_runtime.h>
#include <hip/hip_bf16.h>
#include <stdint.h>

// ---------- types ----------
typedef __attribute__((ext_vector_type(8)))  short bf16x8;
typedef __attribute__((ext_vector_type(4)))  float f32x4;
typedef __attribute__((ext_vector_type(4)))  float float4v;
typedef __attribute__((ext_vector_type(8)))  unsigned short u16x8;
typedef __attribute__((ext_vector_type(4)))  unsigned short u16x4;

#define MFMA16(a,b,c) __builtin_amdgcn_mfma_f32_16x16x32_bf16((a),(b),(c),0,0,0)

__device__ __forceinline__ unsigned short f2bf(float f) {
    unsigned int u = __builtin_bit_cast(unsigned int, f);
    u = (u + 0x7fffu + ((u >> 16) & 1u)) >> 16;
    return (unsigned short)u;
}

__device__ __forceinline__ void gload_lds16(const void* g, void* l) {
    __builtin_amdgcn_global_load_lds(
        (const __attribute__((address_space(1))) void*)g,
        (__attribute__((address_space(3))) void*)l, 16, 0, 0);
}

template<int N> __device__ __forceinline__ void waitvm() {}  // N<0: no wait
template<> __device__ __forceinline__ void waitvm<0>()  { asm volatile("s_waitcnt vmcnt(0)"  ::: "memory"); }
template<> __device__ __forceinline__ void waitvm<8>()  { asm volatile("s_waitcnt vmcnt(8)"  ::: "memory"); }
template<> __device__ __forceinline__ void waitvm<10>() { asm volatile("s_waitcnt vmcnt(10)" ::: "memory"); }
template<> __device__ __forceinline__ void waitvm<12>() { asm volatile("s_waitcnt vmcnt(12)" ::: "memory"); }

// ---------- fp32 -> bf16 convert (for VT only) ----------
__global__ void cvt_f32_bf16(const float* __restrict__ in, unsigned short* __restrict__ out, long n) {
    long i = ((long)blockIdx.x * blockDim.x + threadIdx.x) * 8;
    long stride = (long)gridDim.x * blockDim.x * 8;
    for (; i < n; i += stride) {
        float4v v0 = *(const float4v*)(in + i);
        float4v v1 = *(const float4v*)(in + i + 4);
        u16x8 o;
        o[0] = f2bf(v0[0]); o[1] = f2bf(v0[1]); o[2] = f2bf(v0[2]); o[3] = f2bf(v0[3]);
        o[4] = f2bf(v1[0]); o[5] = f2bf(v1[1]); o[6] = f2bf(v1[2]); o[7] = f2bf(v1[3]);
        *(u16x8*)(out + i) = o;
    }
}

// ---------- GEMM1: z = H(fp32, converted in-kernel) @ VT(bf16)^T ----------
// 256x256 tile, BK=64, 8 waves. A (hs) is read fp32 from global, converted to
// bf16 in-register, and written to LDS with the XOR-granule swizzle via
// conflict-free ds_write_b64. B (vt_bf) staged via global_load_lds as before.
// vmcnt discipline (in-order counting): per tile, issue order is
//   ph0: Bh0(t+1) [2], then sched_barrier, then A(t+2) [8 dwordx4]
//   ph1: Bh1(t+1) [2]
//   ph3: cvt+ds_write A(t+1) (loads issued at t-1 ph0; completion forced by W0)
// waits: W0(end ph0) = vmcnt(10)  -> forces Bh1(t) + A(t+1) complete
//        W3(end ph3) = vmcnt(10)  -> forces Bh0(t+1) complete (A(t+2) untouched)

#define STAGE_B(nB_, k0n, h, l) \
    gload_lds16(pB + ((l)*128 + (h)*32) * 4096L + (k0n), (nB_) + dB0 + ((l)*128 + (h)*32) * 64)

#define LDA(sA_, QM) do { _Pragma("unroll") for (int mi = 0; mi < 4; ++mi) { \
    a[mi][0] = *(const bf16x8*)((sA_) + ((wr*128 + (QM)*64 + mi*16 + lan15) << 6) + g0); \
    a[mi][1] = *(const bf16x8*)((sA_) + ((wr*128 + (QM)*64 + mi*16 + lan15) << 6) + (g0 ^ 32)); } } while (0)
#define LDB(sB_, QN) do { _Pragma("unroll") for (int ni = 0; ni < 2; ++ni) { \
    b[ni][0] = *(const bf16x8*)((sB_) + ((wc*64 + (QN)*32 + ni*16 + lan15) << 6) + g0); \
    b[ni][1] = *(const bf16x8*)((sB_) + ((wc*64 + (QN)*32 + ni*16 + lan15) << 6) + (g0 ^ 32)); } } while (0)

#define DOMFMA(QM, QN) do { __builtin_amdgcn_s_setprio(1); \
    _Pragma("unroll") for (int mi = 0; mi < 4; ++mi) \
      _Pragma("unroll") for (int ni = 0; ni < 2; ++ni) { \
        acc[(QM)*4+mi][(QN)*2+ni] = MFMA16(a[mi][0], b[ni][0], acc[(QM)*4+mi][(QN)*2+ni]); \
        acc[(QM)*4+mi][(QN)*2+ni] = MFMA16(a[mi][1], b[ni][1], acc[(QM)*4+mi][(QN)*2+ni]); } \
    __builtin_amdgcn_s_setprio(0); } while (0)

#define BAR1() do { __builtin_amdgcn_s_barrier(); \
    asm volatile("s_waitcnt lgkmcnt(0)" ::: "memory"); \
    __builtin_amdgcn_sched_barrier(0); } while (0)
#define BAR2() do { __builtin_amdgcn_s_barrier(); \
    __builtin_amdgcn_sched_barrier(0); } while (0)

// A-loads: thread covers rows rbase+4i (i=0..7), 16B of fp32 each, coalesced
// in 16-lane row segments.
#define ALOAD(ar_, kA) do { _Pragma("unroll") for (int ii = 0; ii < 8; ++ii) \
    ar_[ii] = *(const float4v*)(pAf + (long)ii * 16384 + (kA)); } while (0)

// cvt + swizzled ds_write_b64 (conflict-free: each 16-lane group covers all
// 32 banks exactly once per instruction)
#define ACVT(dst_, ar_) do { _Pragma("unroll") for (int ii = 0; ii < 8; ++ii) { \
    u16x4 pk; pk[0] = f2bf(ar_[ii][0]); pk[1] = f2bf(ar_[ii][1]); \
              pk[2] = f2bf(ar_[ii][2]); pk[3] = f2bf(ar_[ii][3]); \
    const int rl = rbase + ii * 4; \
    *(u16x4*)((dst_) + rl * 64 + ((gA ^ (rl & 7)) << 3) + hA) = pk; } } while (0)

#define KTILE2(cbA_, cbB_, nbA_, nbB_, kB, kA, arI_, arC_, DOSTAGE, V0, V3) do { \
    LDA(cbA_, 0); LDB(cbB_, 0); \
    if (DOSTAGE) { STAGE_B(nbB_, kB, 0, 0); STAGE_B(nbB_, kB, 0, 1); \
                   __builtin_amdgcn_sched_barrier(0); \
                   ALOAD(arI_, kA); } \
    BAR1(); DOMFMA(0, 0); waitvm<V0>(); BAR2(); \
    LDB(cbB_, 1); \
    if (DOSTAGE) { STAGE_B(nbB_, kB, 1, 0); STAGE_B(nbB_, kB, 1, 1); } \
    BAR1(); DOMFMA(0, 1); BAR2(); \
    LDA(cbA_, 1); \
    BAR1(); DOMFMA(1, 1); BAR2(); \
    LDB(cbB_, 0); \
    if (DOSTAGE) { ACVT(nbA_, arC_); } \
    BAR1(); DOMFMA(1, 0); waitvm<V3>(); BAR2(); \
} while (0)

__global__ __launch_bounds__(512, 2) void gemm1_8ph(const float* __restrict__ Af,           // [16384][4096] fp32
                                                    const unsigned short* __restrict__ B,   // [2048][4096] bf16
                                                    unsigned short* __restrict__ Z) {       // [16384][2048] bf16
    __shared__ __align__(16) unsigned short lds[65536];   // 128 KiB

    const int tid   = threadIdx.x;
    const int lane  = tid & 63;
    const int wid   = tid >> 6;
    const int wr    = wid >> 2;
    const int wc    = wid & 3;
    const int lan15 = lane & 15;
    const int g0    = (((lane >> 4) ^ (lane & 7)) << 3);

    const int  bid = blockIdx.x;
    const long m0  = (long)(bid >> 3) * 256;
    const long n0  = (long)(bid & 7) * 256;

    // B staging addressing (bf16, inverse-swizzled global source)
    const int q8    = tid >> 3;
    const int granA = (((tid & 7) ^ (q8 & 7)) << 3);
    const int rB0   = (q8 & 31) + ((q8 >> 5) << 6);
    const unsigned short* pB = B + (n0 + rB0) * 4096L + granA;
    const int dB0   = ((wid & 3) * 8 + ((wid >> 2) << 6)) * 64;

    // A fp32 load addressing: rbase = wid*32 + (lane>>4), cols (lane&15)*4
    const int rbase = wid * 32 + (lane >> 4);
    const float* pAf = Af + (m0 + rbase) * 4096L + (lan15 & 15) * 4;
    const int gA = lan15 >> 1;           // logical granule
    const int hA = (lane & 1) * 4;       // half-granule elem offset

    f32x4 acc[8][4] = {};
    bf16x8 a[4][2], b[2][2];
    float4v arE[8], arO[8];

    unsigned short* buf0 = lds;
    unsigned short* buf1 = lds + 32768;

    // ---- prologue ----
    ALOAD(arE, 0);                               // A(0)
    STAGE_B(buf0 + 16384, 0, 0, 0); STAGE_B(buf0 + 16384, 0, 0, 1);
    STAGE_B(buf0 + 16384, 0, 1, 0); STAGE_B(buf0 + 16384, 0, 1, 1);
    __builtin_amdgcn_sched_barrier(0);
    ALOAD(arO, 64);                              // A(1)
    waitvm<12>();                                // A(0) done
    ACVT(buf0, arE);                             // write A(0) -> buf0
    waitvm<8>();                                 // B(0) done
    asm volatile("s_waitcnt lgkmcnt(0)" ::: "memory");
    __builtin_amdgcn_s_barrier();
    __builtin_amdgcn_sched_barrier(0);

    // ---- main loop: t = 0..61, unrolled x2 for static A-reg sets ----
    for (int it = 0; it < 31; ++it) {
        const int t = it * 2;
        // even tile t: cb=buf0, nb=buf1; issue A(t+2)->arE, cvt A(t+1) from arO
        KTILE2(buf0, buf0 + 16384, buf1, buf1 + 16384,
               (t + 1) * 64, (t + 2) * 64, arE, arO, true, 10, 10);
        // odd tile t+1: cb=buf1, nb=buf0; issue A(t+3)->arO, cvt A(t+2) from arE
        KTILE2(buf1, buf1 + 16384, buf0, buf0 + 16384,
               (t + 2) * 64, (t + 3) * 64, arO, arE, true, 10, 10);
    }
    // t=62 (even): stage B(63), dummy A issue (clamped to tile 63), cvt A(63) from arO
    KTILE2(buf0, buf0 + 16384, buf1, buf1 + 16384,
           63 * 64, 63 * 64, arE, arO, true, 10, 10);
    // t=63 (odd): no staging; drain
    KTILE2(buf1, buf1 + 16384, buf0, buf0 + 16384,
           0, 0, arE, arO, false, 0, -1);

    // ---- epilogue: z bf16 store ----
    const int rq = (lane >> 4) << 2;
    #pragma unroll
    for (int mi = 0; mi < 8; ++mi) {
        #pragma unroll
        for (int ni = 0; ni < 4; ++ni) {
            const long mb  = m0 + wr * 128 + mi * 16 + rq;
            const long nb2 = n0 + wc * 64 + ni * 16 + lan15;
            #pragma unroll
            for (int j = 0; j < 4; ++j)
                Z[(mb + j) * 2048L + nb2] = f2bf(acc[mi][ni][j]);
        }
    }
}

// ---------- GEMM2: grouped up-projection (round-2 version) ----------
#define U_PAD 80

__global__ __launch_bounds__(256) void gemm2(const unsigned short* __restrict__ Z,  // [16384][2048] bf16
                                             const float* __restrict__ U,           // [32][128][64] f32
                                             float* __restrict__ out) {             // [16384][4096] f32
    __shared__ __align__(16) unsigned short lU[128 * U_PAD];

    const int tid  = threadIdx.x;
    const int lane = tid & 63;
    const int wid  = tid >> 6;
    const int g    = blockIdx.x & 31;
    const long m0  = (long)(blockIdx.x >> 5) * 64;

    const float* ug = U + (long)g * (128 * 64);
    for (int i = tid; i < (128 * 64) / 4; i += 256) {
        const int r = i >> 4;
        const int c = (i << 2) & 63;
        float4v v = *(const float4v*)(ug + i * 4);
        unsigned short* d = &lU[r * U_PAD + c];
        d[0] = f2bf(v[0]); d[1] = f2bf(v[1]); d[2] = f2bf(v[2]); d[3] = f2bf(v[3]);
    }
    __syncthreads();

    const long mrow = m0 + wid * 16 + (lane & 15);
    const unsigned short* zrow = Z + mrow * 2048L + g * 64 + ((lane >> 4) << 3);
    const bf16x8 a0 = *(const bf16x8*)(zrow);
    const bf16x8 a1 = *(const bf16x8*)(zrow + 32);

    f32x4 acc[8] = {};
    const int blds = (lane & 15);
    const int kofs = (lane >> 4) << 3;
    #pragma unroll
    for (int ni = 0; ni < 8; ++ni) {
        const bf16x8 b0 = *(const bf16x8*)&lU[(ni * 16 + blds) * U_PAD + kofs];
        const bf16x8 b1 = *(const bf16x8*)&lU[(ni * 16 + blds) * U_PAD + 32 + kofs];
        acc[ni] = MFMA16(a0, b0, acc[ni]);
        acc[ni] = MFMA16(a1, b1, acc[ni]);
    }

    const long mb = m0 + wid * 16 + ((lane >> 4) << 2);
    const long cb = (long)g * 128 + (lane & 15);
    #pragma unroll
    for (int ni = 0; ni < 8; ++ni)
        #pragma unroll
        for (int j = 0; j < 4; ++j)
            out[(mb + j) * 4096L + cb + ni * 16] = acc[ni][j];
}

// ---------- launch ----------
extern "C" void kernel_launch(void* const* d_in, const int* in_sizes, int n_in,
                              void* d_out, int out_size, void* d_ws, size_t ws_size,
                              hipStream_t stream) {
    const float* hs = (const float*)d_in[0];   // [4,4096,4096] fp32
    const float* vt = (const float*)d_in[1];   // [2048,4096]   fp32
    const float* uw = (const float*)d_in[2];   // [32,128,64]   fp32
    float* out = (float*)d_out;

    unsigned short* vt_bf = (unsigned short*)d_ws;            // 8388608 bf16
    unsigned short* z_bf  = vt_bf + 8388608L;                 // 33554432 bf16

    cvt_f32_bf16<<<512, 256, 0, stream>>>(vt, vt_bf, 8388608L);

    // GEMM1: (16384/256) x (2048/256) = 64 x 8 = 512 blocks, 512 threads
    gemm1_8ph<<<512, 512, 0, stream>>>(hs, vt_bf, z_bf);

    // GEMM2: (16384/64) x 32 groups = 8192 blocks
    gemm2<<<8192, 256, 0, stream>>>(z_bf, uw, out);
}

// Round 5
// 464.453 us; speedup vs baseline: 2.0738x; 2.0738x over previous
//
#include <hip/hip_runtime.h>
#include <hip/hip_bf16.h>
#include <stdint.h>

// ---------- types ----------
typedef __attribute__((ext_vector_type(8)))  short bf16x8;
typedef __attribute__((ext_vector_type(4)))  float f32x4;
typedef __attribute__((ext_vector_type(4)))  float float4v;
typedef __attribute__((ext_vector_type(8)))  unsigned short u16x8;
typedef __attribute__((ext_vector_type(4)))  unsigned short u16x4;

#define MFMA16(a,b,c) __builtin_amdgcn_mfma_f32_16x16x32_bf16((a),(b),(c),0,0,0)

__device__ __forceinline__ unsigned short f2bf(float f) {
    unsigned int u = __builtin_bit_cast(unsigned int, f);
    u = (u + 0x7fffu + ((u >> 16) & 1u)) >> 16;
    return (unsigned short)u;
}

__device__ __forceinline__ void gload_lds16(const void* g, void* l) {
    __builtin_amdgcn_global_load_lds(
        (const __attribute__((address_space(1))) void*)g,
        (__attribute__((address_space(3))) void*)l, 16, 0, 0);
}

template<int N> __device__ __forceinline__ void waitvm() {}  // N<0: no wait
template<> __device__ __forceinline__ void waitvm<0>()  { asm volatile("s_waitcnt vmcnt(0)"  ::: "memory"); }
template<> __device__ __forceinline__ void waitvm<2>()  { asm volatile("s_waitcnt vmcnt(2)"  ::: "memory"); }
template<> __device__ __forceinline__ void waitvm<10>() { asm volatile("s_waitcnt vmcnt(10)" ::: "memory"); }

// ---------- fp32 -> bf16 convert (VT only; 16 MB pass, ~8 us) ----------
__global__ void cvt_f32_bf16(const float* __restrict__ in, unsigned short* __restrict__ out, long n) {
    long i = ((long)blockIdx.x * blockDim.x + threadIdx.x) * 8;
    long stride = (long)gridDim.x * blockDim.x * 8;
    for (; i < n; i += stride) {
        float4v v0 = *(const float4v*)(in + i);
        float4v v1 = *(const float4v*)(in + i + 4);
        u16x8 o;
        o[0] = f2bf(v0[0]); o[1] = f2bf(v0[1]); o[2] = f2bf(v0[2]); o[3] = f2bf(v0[3]);
        o[4] = f2bf(v1[0]); o[5] = f2bf(v1[1]); o[6] = f2bf(v1[2]); o[7] = f2bf(v1[3]);
        *(u16x8*)(out + i) = o;
    }
}

// ---------- GEMM1: z = H(fp32, cvt in-kernel) @ VT(bf16)^T ----------
// Round-2 verified 8-phase skeleton (261 us, 0 conflicts). Only change: A is
// staged fp32->reg->bf16->LDS, 1-DEEP (ar[8] = 32 VGPR, written same tile),
// instead of the hs-cvt prepass + global_load_lds.
// Issue order per tile t: ph0 [Bh0(t+1) x2, A(t+1) x8], ph1 [Bh1(t+1) x2].
// Waits: W0 = vmcnt(10) forces Bh1(t); vmcnt(2) before ACVT forces A(t+1)+Bh0(t+1).

#define STAGE_B(nB_, k0n, h, l) \
    gload_lds16(pB + ((l)*128 + (h)*32) * 4096L + (k0n), (nB_) + dB0 + ((l)*128 + (h)*32) * 64)

#define LDA(sA_, QM) do { _Pragma("unroll") for (int mi = 0; mi < 4; ++mi) { \
    a[mi][0] = *(const bf16x8*)((sA_) + ((wr*128 + (QM)*64 + mi*16 + lan15) << 6) + g0); \
    a[mi][1] = *(const bf16x8*)((sA_) + ((wr*128 + (QM)*64 + mi*16 + lan15) << 6) + (g0 ^ 32)); } } while (0)
#define LDB(sB_, QN) do { _Pragma("unroll") for (int ni = 0; ni < 2; ++ni) { \
    b[ni][0] = *(const bf16x8*)((sB_) + ((wc*64 + (QN)*32 + ni*16 + lan15) << 6) + g0); \
    b[ni][1] = *(const bf16x8*)((sB_) + ((wc*64 + (QN)*32 + ni*16 + lan15) << 6) + (g0 ^ 32)); } } while (0)

#define DOMFMA(QM, QN) do { __builtin_amdgcn_s_setprio(1); \
    _Pragma("unroll") for (int mi = 0; mi < 4; ++mi) \
      _Pragma("unroll") for (int ni = 0; ni < 2; ++ni) { \
        acc[(QM)*4+mi][(QN)*2+ni] = MFMA16(a[mi][0], b[ni][0], acc[(QM)*4+mi][(QN)*2+ni]); \
        acc[(QM)*4+mi][(QN)*2+ni] = MFMA16(a[mi][1], b[ni][1], acc[(QM)*4+mi][(QN)*2+ni]); } \
    __builtin_amdgcn_s_setprio(0); } while (0)

#define BAR1() do { __builtin_amdgcn_s_barrier(); \
    asm volatile("s_waitcnt lgkmcnt(0)" ::: "memory"); \
    __builtin_amdgcn_sched_barrier(0); } while (0)
#define BAR2() do { __builtin_amdgcn_s_barrier(); \
    __builtin_amdgcn_sched_barrier(0); } while (0)

// A-loads: row rl = wid*32 + (lane>>4) + 4*ii, cols lan15*4 .. +3 (fp32, 16B).
// 16 lanes x 16B = 256B contiguous per row segment.
#define ALOAD(ar_, kA) do { _Pragma("unroll") for (int ii = 0; ii < 8; ++ii) \
    ar_[ii] = *(const float4v*)(pAf + (long)ii * 16384 + (kA)); } while (0)

// cvt + swizzled ds_write_b64; layout matches LDA: elem(row,c) at
// row*64 + ((c>>3 ^ (row&7))<<3) + (c&7). Conflict-free (each 16-lane row
// group covers 128B; wave = 2-way aliasing = free per m136).
#define ACVT(dst_, ar_) do { _Pragma("unroll") for (int ii = 0; ii < 8; ++ii) { \
    u16x4 pk; pk[0] = f2bf(ar_[ii][0]); pk[1] = f2bf(ar_[ii][1]); \
              pk[2] = f2bf(ar_[ii][2]); pk[3] = f2bf(ar_[ii][3]); \
    const int rl = rbase + ii * 4; \
    *(u16x4*)((dst_) + rl * 64 + ((gA ^ (rl & 7)) << 3) + hA) = pk; } } while (0)

#define KTILE(cbA_, cbB_, nbA_, nbB_, kB, DOSTAGE, V0) do { \
    LDA(cbA_, 0); LDB(cbB_, 0); \
    if (DOSTAGE) { STAGE_B(nbB_, kB, 0, 0); STAGE_B(nbB_, kB, 0, 1); \
                   __builtin_amdgcn_sched_barrier(0); \
                   ALOAD(ar, kB); } \
    BAR1(); DOMFMA(0, 0); waitvm<V0>(); BAR2(); \
    LDB(cbB_, 1); \
    if (DOSTAGE) { STAGE_B(nbB_, kB, 1, 0); STAGE_B(nbB_, kB, 1, 1); } \
    BAR1(); DOMFMA(0, 1); BAR2(); \
    LDA(cbA_, 1); \
    BAR1(); DOMFMA(1, 1); BAR2(); \
    LDB(cbB_, 0); \
    if (DOSTAGE) { waitvm<2>(); ACVT(nbA_, ar); } \
    BAR1(); DOMFMA(1, 0); BAR2(); \
} while (0)

__global__ __launch_bounds__(512, 2) void gemm1_8ph(const float* __restrict__ Af,           // [16384][4096] fp32
                                                    const unsigned short* __restrict__ B,   // [2048][4096] bf16
                                                    unsigned short* __restrict__ Z) {       // [16384][2048] bf16
    __shared__ __align__(16) unsigned short lds[65536];   // 128 KiB

    const int tid   = threadIdx.x;
    const int lane  = tid & 63;
    const int wid   = tid >> 6;
    const int wr    = wid >> 2;
    const int wc    = wid & 3;
    const int lan15 = lane & 15;
    const int g0    = (((lane >> 4) ^ (lane & 7)) << 3);

    const int  bid = blockIdx.x;
    const long m0  = (long)(bid >> 3) * 256;
    const long n0  = (long)(bid & 7) * 256;

    // B staging addressing (bf16, inverse-swizzled global source)
    const int q8    = tid >> 3;
    const int granB = (((tid & 7) ^ (q8 & 7)) << 3);
    const int rB0   = (q8 & 31) + ((q8 >> 5) << 6);
    const unsigned short* pB = B + (n0 + rB0) * 4096L + granB;
    const int dB0   = ((wid & 3) * 8 + ((wid >> 2) << 6)) * 64;

    // A fp32 load addressing
    const int rbase = wid * 32 + (lane >> 4);
    const float* pAf = Af + (m0 + rbase) * 4096L + lan15 * 4;
    const int gA = lan15 >> 1;
    const int hA = (lane & 1) * 4;

    f32x4 acc[8][4] = {};
    bf16x8 a[4][2], b[2][2];
    float4v ar[8];

    unsigned short* buf0 = lds;
    unsigned short* buf1 = lds + 32768;

    // ---- prologue: tile 0 ----
    ALOAD(ar, 0);
    STAGE_B(buf0 + 16384, 0, 0, 0); STAGE_B(buf0 + 16384, 0, 0, 1);
    STAGE_B(buf0 + 16384, 0, 1, 0); STAGE_B(buf0 + 16384, 0, 1, 1);
    ACVT(buf0, ar);                 // compiler waits vmcnt for ar regs
    waitvm<0>();                    // force B(0)
    asm volatile("s_waitcnt lgkmcnt(0)" ::: "memory");
    __builtin_amdgcn_s_barrier();
    __builtin_amdgcn_sched_barrier(0);

    // ---- main loop ----
    for (int t = 0; t < 63; ++t) {
        unsigned short* cb = (t & 1) ? buf1 : buf0;
        unsigned short* nb = (t & 1) ? buf0 : buf1;
        KTILE(cb, cb + 16384, nb, nb + 16384, (t + 1) * 64, true, 10);
    }
    // t=63 (parity 1): no staging; W0 drains leftover Bh1(63)
    KTILE(buf1, buf1 + 16384, buf0, buf0 + 16384, 0, false, 0);

    // ---- epilogue: z bf16 store ----
    const int rq = (lane >> 4) << 2;
    #pragma unroll
    for (int mi = 0; mi < 8; ++mi) {
        #pragma unroll
        for (int ni = 0; ni < 4; ++ni) {
            const long mb  = m0 + wr * 128 + mi * 16 + rq;
            const long nb2 = n0 + wc * 64 + ni * 16 + lan15;
            #pragma unroll
            for (int j = 0; j < 4; ++j)
                Z[(mb + j) * 2048L + nb2] = f2bf(acc[mi][ni][j]);
        }
    }
}

// ---------- GEMM2: grouped up-projection (round-2 version, write-BW-bound) ----------
#define U_PAD 80

__global__ __launch_bounds__(256) void gemm2(const unsigned short* __restrict__ Z,  // [16384][2048] bf16
                                             const float* __restrict__ U,           // [32][128][64] f32
                                             float* __restrict__ out) {             // [16384][4096] f32
    __shared__ __align__(16) unsigned short lU[128 * U_PAD];

    const int tid  = threadIdx.x;
    const int lane = tid & 63;
    const int wid  = tid >> 6;
    const int g    = blockIdx.x & 31;
    const long m0  = (long)(blockIdx.x >> 5) * 64;

    const float* ug = U + (long)g * (128 * 64);
    for (int i = tid; i < (128 * 64) / 4; i += 256) {
        const int r = i >> 4;
        const int c = (i << 2) & 63;
        float4v v = *(const float4v*)(ug + i * 4);
        unsigned short* d = &lU[r * U_PAD + c];
        d[0] = f2bf(v[0]); d[1] = f2bf(v[1]); d[2] = f2bf(v[2]); d[3] = f2bf(v[3]);
    }
    __syncthreads();

    const long mrow = m0 + wid * 16 + (lane & 15);
    const unsigned short* zrow = Z + mrow * 2048L + g * 64 + ((lane >> 4) << 3);
    const bf16x8 a0 = *(const bf16x8*)(zrow);
    const bf16x8 a1 = *(const bf16x8*)(zrow + 32);

    f32x4 acc[8] = {};
    const int blds = (lane & 15);
    const int kofs = (lane >> 4) << 3;
    #pragma unroll
    for (int ni = 0; ni < 8; ++ni) {
        const bf16x8 b0 = *(const bf16x8*)&lU[(ni * 16 + blds) * U_PAD + kofs];
        const bf16x8 b1 = *(const bf16x8*)&lU[(ni * 16 + blds) * U_PAD + 32 + kofs];
        acc[ni] = MFMA16(a0, b0, acc[ni]);
        acc[ni] = MFMA16(a1, b1, acc[ni]);
    }

    const long mb = m0 + wid * 16 + ((lane >> 4) << 2);
    const long cb = (long)g * 128 + (lane & 15);
    #pragma unroll
    for (int ni = 0; ni < 8; ++ni)
        #pragma unroll
        for (int j = 0; j < 4; ++j)
            out[(mb + j) * 4096L + cb + ni * 16] = acc[ni][j];
}

// ---------- launch ----------
extern "C" void kernel_launch(void* const* d_in, const int* in_sizes, int n_in,
                              void* d_out, int out_size, void* d_ws, size_t ws_size,
                              hipStream_t stream) {
    const float* hs = (const float*)d_in[0];   // [4,4096,4096] fp32
    const float* vt = (const float*)d_in[1];   // [2048,4096]   fp32
    const float* uw = (const float*)d_in[2];   // [32,128,64]   fp32
    float* out = (float*)d_out;

    unsigned short* vt_bf = (unsigned short*)d_ws;            // 8388608 bf16
    unsigned short* z_bf  = vt_bf + 8388608L;                 // 33554432 bf16

    cvt_f32_bf16<<<512, 256, 0, stream>>>(vt, vt_bf, 8388608L);

    // GEMM1: (16384/256) x (2048/256) = 64 x 8 = 512 blocks, 512 threads
    gemm1_8ph<<<512, 512, 0, stream>>>(hs, vt_bf, z_bf);

    // GEMM2: (16384/64) x 32 groups = 8192 blocks
    gemm2<<<8192, 256, 0, stream>>>(z_bf, uw, out);
}

// Round 6
// 373.453 us; speedup vs baseline: 2.5791x; 1.2437x over previous
//
#include <hip/hip_runtime.h>
#include <hip/hip_bf16.h>
#include <stdint.h>

// ---------- types ----------
typedef __attribute__((ext_vector_type(8)))  short bf16x8;
typedef __attribute__((ext_vector_type(4)))  float f32x4;
typedef __attribute__((ext_vector_type(4)))  float float4v;
typedef __attribute__((ext_vector_type(8)))  unsigned short u16x8;

#define MFMA16(a,b,c) __builtin_amdgcn_mfma_f32_16x16x32_bf16((a),(b),(c),0,0,0)

__device__ __forceinline__ unsigned short f2bf(float f) {
    unsigned int u = __builtin_bit_cast(unsigned int, f);
    u = (u + 0x7fffu + ((u >> 16) & 1u)) >> 16;
    return (unsigned short)u;
}

__device__ __forceinline__ void gload_lds16(const void* g, void* l) {
    __builtin_amdgcn_global_load_lds(
        (const __attribute__((address_space(1))) void*)g,
        (__attribute__((address_space(3))) void*)l, 16, 0, 0);
}

template<int N> __device__ __forceinline__ void waitvm() {}  // N<0: no wait
template<> __device__ __forceinline__ void waitvm<6>() { asm volatile("s_waitcnt vmcnt(6)" ::: "memory"); }
template<> __device__ __forceinline__ void waitvm<4>() { asm volatile("s_waitcnt vmcnt(4)" ::: "memory"); }
template<> __device__ __forceinline__ void waitvm<2>() { asm volatile("s_waitcnt vmcnt(2)" ::: "memory"); }
template<> __device__ __forceinline__ void waitvm<0>() { asm volatile("s_waitcnt vmcnt(0)" ::: "memory"); }

// ---------- fp32 -> bf16 convert ----------
__global__ void cvt_f32_bf16(const float* __restrict__ in, unsigned short* __restrict__ out, long n) {
    long i = ((long)blockIdx.x * blockDim.x + threadIdx.x) * 8;
    long stride = (long)gridDim.x * blockDim.x * 8;
    for (; i < n; i += stride) {
        float4v v0 = *(const float4v*)(in + i);
        float4v v1 = *(const float4v*)(in + i + 4);
        u16x8 o;
        o[0] = f2bf(v0[0]); o[1] = f2bf(v0[1]); o[2] = f2bf(v0[2]); o[3] = f2bf(v0[3]);
        o[4] = f2bf(v1[0]); o[5] = f2bf(v1[1]); o[6] = f2bf(v1[2]); o[7] = f2bf(v1[3]);
        *(u16x8*)(out + i) = o;
    }
}

// ---------- GEMM1: z = H(bf16) @ VT(bf16)^T, 256x256 tile, 8-phase ----------
// Round-2 verified skeleton (261 us, 0 conflicts). Delta this round: B-quadrant
// fragments held in separate register sets b0/b1 so ph3 re-reads NOTHING from
// LDS (28 -> 24 ds_read_b128 per tile per wave; DS pipe leaves the critical path).

#define STAGE_A(nA_, k0n, h, l) \
    gload_lds16(pA + ((l)*128 + (h)*64) * 4096L + (k0n), (nA_) + dA0 + ((l)*128 + (h)*64) * 64)
#define STAGE_B(nB_, k0n, h, l) \
    gload_lds16(pB + ((l)*128 + (h)*32) * 4096L + (k0n), (nB_) + dB0 + ((l)*128 + (h)*32) * 64)

#define LDA(sA_, QM) do { _Pragma("unroll") for (int mi = 0; mi < 4; ++mi) { \
    a[mi][0] = *(const bf16x8*)((sA_) + ((wr*128 + (QM)*64 + mi*16 + lan15) << 6) + g0); \
    a[mi][1] = *(const bf16x8*)((sA_) + ((wr*128 + (QM)*64 + mi*16 + lan15) << 6) + (g0 ^ 32)); } } while (0)
#define LDB(dst_, sB_, QN) do { _Pragma("unroll") for (int ni = 0; ni < 2; ++ni) { \
    dst_[ni][0] = *(const bf16x8*)((sB_) + ((wc*64 + (QN)*32 + ni*16 + lan15) << 6) + g0); \
    dst_[ni][1] = *(const bf16x8*)((sB_) + ((wc*64 + (QN)*32 + ni*16 + lan15) << 6) + (g0 ^ 32)); } } while (0)

#define DOMFMA(QM, QN, bset_) do { __builtin_amdgcn_s_setprio(1); \
    _Pragma("unroll") for (int mi = 0; mi < 4; ++mi) \
      _Pragma("unroll") for (int ni = 0; ni < 2; ++ni) { \
        acc[(QM)*4+mi][(QN)*2+ni] = MFMA16(a[mi][0], bset_[ni][0], acc[(QM)*4+mi][(QN)*2+ni]); \
        acc[(QM)*4+mi][(QN)*2+ni] = MFMA16(a[mi][1], bset_[ni][1], acc[(QM)*4+mi][(QN)*2+ni]); } \
    __builtin_amdgcn_s_setprio(0); } while (0)

#define BAR1() do { __builtin_amdgcn_s_barrier(); \
    asm volatile("s_waitcnt lgkmcnt(0)" ::: "memory"); \
    __builtin_amdgcn_sched_barrier(0); } while (0)
#define BAR2() do { __builtin_amdgcn_s_barrier(); \
    __builtin_amdgcn_sched_barrier(0); } while (0)

#define KTILE(sA_, sB_, nA_, nB_, k0n, DOSTAGE, V0, V1, V3) do { \
    /* ph0: Q(0,0) <- Ah0 x Bh0 */ \
    LDA(sA_, 0); LDB(b0, sB_, 0); \
    if (DOSTAGE) { STAGE_A(nA_, k0n, 0, 0); STAGE_A(nA_, k0n, 0, 1); \
                   STAGE_B(nB_, k0n, 0, 0); STAGE_B(nB_, k0n, 0, 1); } \
    BAR1(); DOMFMA(0, 0, b0); waitvm<V0>(); BAR2(); \
    /* ph1: Q(0,1) <- Ah0 x Bh1 */ \
    LDB(b1, sB_, 1); \
    if (DOSTAGE) { STAGE_B(nB_, k0n, 1, 0); STAGE_B(nB_, k0n, 1, 1); } \
    BAR1(); DOMFMA(0, 1, b1); waitvm<V1>(); BAR2(); \
    /* ph2: Q(1,1) <- Ah1 x Bh1 */ \
    LDA(sA_, 1); \
    if (DOSTAGE) { STAGE_A(nA_, k0n, 1, 0); STAGE_A(nA_, k0n, 1, 1); } \
    BAR1(); DOMFMA(1, 1, b1); BAR2(); \
    /* ph3: Q(1,0) <- Ah1 x Bh0 (b0 kept in regs; zero ds_reads) */ \
    BAR1(); DOMFMA(1, 0, b0); waitvm<V3>(); BAR2(); \
} while (0)

__global__ __launch_bounds__(512, 2) void gemm1_8ph(const unsigned short* __restrict__ A,  // [16384][4096]
                                                    const unsigned short* __restrict__ B,  // [2048][4096]
                                                    unsigned short* __restrict__ Z) {      // [16384][2048]
    __shared__ __align__(16) unsigned short lds[65536];   // 128 KiB

    const int tid   = threadIdx.x;
    const int lane  = tid & 63;
    const int wid   = tid >> 6;
    const int wr    = wid >> 2;          // 0..1
    const int wc    = wid & 3;           // 0..3
    const int lan15 = lane & 15;
    const int g0    = (((lane >> 4) ^ (lane & 7)) << 3);

    const int  bid = blockIdx.x;
    const long m0  = (long)(bid >> 3) * 256;
    const long n0  = (long)(bid & 7) * 256;

    const int q8    = tid >> 3;
    const int granA = (((tid & 7) ^ (q8 & 7)) << 3);
    const unsigned short* pA = A + (m0 + q8) * 4096L + granA;
    const int rB0   = (q8 & 31) + ((q8 >> 5) << 6);
    const unsigned short* pB = B + (n0 + rB0) * 4096L + granA;
    const int dA0   = (wid * 8) * 64;
    const int dB0   = ((wid & 3) * 8 + ((wid >> 2) << 6)) * 64;

    f32x4 acc[8][4] = {};
    bf16x8 a[4][2], b0[2][2], b1[2][2];

    unsigned short* buf0 = lds;
    unsigned short* buf1 = lds + 32768;

    // prologue: stage tile 0 (issue order Ah0, Bh0, Bh1, Ah1); keep last 2 halves in flight
    STAGE_A(buf0, 0, 0, 0); STAGE_A(buf0, 0, 0, 1);
    STAGE_B(buf0 + 16384, 0, 0, 0); STAGE_B(buf0 + 16384, 0, 0, 1);
    STAGE_B(buf0 + 16384, 0, 1, 0); STAGE_B(buf0 + 16384, 0, 1, 1);
    STAGE_A(buf0, 0, 1, 0); STAGE_A(buf0, 0, 1, 1);
    waitvm<4>();
    BAR2();

    for (int t = 0; t < 63; ++t) {
        unsigned short* cb = (t & 1) ? buf1 : buf0;
        unsigned short* nb = (t & 1) ? buf0 : buf1;
        KTILE(cb, cb + 16384, nb, nb + 16384, (t + 1) * 64, true, 6, 6, 4);
    }
    // last tile (t=63, parity 1): no staging; drain 2 -> 0
    KTILE(buf1, buf1 + 16384, buf0, buf0 + 16384, 0, false, 2, 0, -1);

    // epilogue: C/D col = lane&15 (n), row = (lane>>4)*4+j (m)
    const int rq = (lane >> 4) << 2;
    #pragma unroll
    for (int mi = 0; mi < 8; ++mi) {
        #pragma unroll
        for (int ni = 0; ni < 4; ++ni) {
            const long mb  = m0 + wr * 128 + mi * 16 + rq;
            const long nb2 = n0 + wc * 64 + ni * 16 + lan15;
            #pragma unroll
            for (int j = 0; j < 4; ++j)
                Z[(mb + j) * 2048L + nb2] = f2bf(acc[mi][ni][j]);
        }
    }
}

// ---------- GEMM2: grouped up-projection (round-2 version, at write-BW floor) ----------
#define U_PAD 80

__global__ __launch_bounds__(256) void gemm2(const unsigned short* __restrict__ Z,  // [16384][2048] bf16
                                             const float* __restrict__ U,           // [32][128][64] f32
                                             float* __restrict__ out) {             // [16384][4096] f32
    __shared__ __align__(16) unsigned short lU[128 * U_PAD];

    const int tid  = threadIdx.x;
    const int lane = tid & 63;
    const int wid  = tid >> 6;
    const int g    = blockIdx.x & 31;
    const long m0  = (long)(blockIdx.x >> 5) * 64;

    const float* ug = U + (long)g * (128 * 64);
    for (int i = tid; i < (128 * 64) / 4; i += 256) {
        const int r = i >> 4;
        const int c = (i << 2) & 63;
        float4v v = *(const float4v*)(ug + i * 4);
        unsigned short* d = &lU[r * U_PAD + c];
        d[0] = f2bf(v[0]); d[1] = f2bf(v[1]); d[2] = f2bf(v[2]); d[3] = f2bf(v[3]);
    }
    __syncthreads();

    const long mrow = m0 + wid * 16 + (lane & 15);
    const unsigned short* zrow = Z + mrow * 2048L + g * 64 + ((lane >> 4) << 3);
    const bf16x8 a0 = *(const bf16x8*)(zrow);
    const bf16x8 a1 = *(const bf16x8*)(zrow + 32);

    f32x4 acc[8] = {};
    const int blds = (lane & 15);
    const int kofs = (lane >> 4) << 3;
    #pragma unroll
    for (int ni = 0; ni < 8; ++ni) {
        const bf16x8 c0 = *(const bf16x8*)&lU[(ni * 16 + blds) * U_PAD + kofs];
        const bf16x8 c1 = *(const bf16x8*)&lU[(ni * 16 + blds) * U_PAD + 32 + kofs];
        acc[ni] = MFMA16(a0, c0, acc[ni]);
        acc[ni] = MFMA16(a1, c1, acc[ni]);
    }

    const long mb = m0 + wid * 16 + ((lane >> 4) << 2);
    const long cb = (long)g * 128 + (lane & 15);
    #pragma unroll
    for (int ni = 0; ni < 8; ++ni)
        #pragma unroll
        for (int j = 0; j < 4; ++j)
            out[(mb + j) * 4096L + cb + ni * 16] = acc[ni][j];
}

// ---------- launch ----------
extern "C" void kernel_launch(void* const* d_in, const int* in_sizes, int n_in,
                              void* d_out, int out_size, void* d_ws, size_t ws_size,
                              hipStream_t stream) {
    const float* hs = (const float*)d_in[0];   // [4,4096,4096] fp32
    const float* vt = (const float*)d_in[1];   // [2048,4096]   fp32
    const float* uw = (const float*)d_in[2];   // [32,128,64]   fp32
    float* out = (float*)d_out;

    unsigned short* hs_bf = (unsigned short*)d_ws;            // 67108864 bf16
    unsigned short* vt_bf = hs_bf + 67108864L;                //  8388608 bf16
    unsigned short* z_bf  = vt_bf + 8388608L;                 // 33554432 bf16

    cvt_f32_bf16<<<2048, 256, 0, stream>>>(hs, hs_bf, 67108864L);
    cvt_f32_bf16<<<512, 256, 0, stream>>>(vt, vt_bf, 8388608L);

    // GEMM1: (16384/256) x (2048/256) = 64 x 8 = 512 blocks, 512 threads
    gemm1_8ph<<<512, 512, 0, stream>>>(hs_bf, vt_bf, z_bf);

    // GEMM2: (16384/64) x 32 groups = 8192 blocks
    gemm2<<<8192, 256, 0, stream>>>(z_bf, uw, out);
}

// Round 7
// 363.981 us; speedup vs baseline: 2.6462x; 1.0260x over previous
//
#include <hip/hip_runtime.h>
#include <hip/hip_bf16.h>
#include <stdint.h>

// ---------- types ----------
typedef __attribute__((ext_vector_type(8)))  short bf16x8;
typedef __attribute__((ext_vector_type(4)))  float f32x4;
typedef __attribute__((ext_vector_type(4)))  float float4v;
typedef __attribute__((ext_vector_type(8)))  unsigned short u16x8;

#define MFMA16(a,b,c) __builtin_amdgcn_mfma_f32_16x16x32_bf16((a),(b),(c),0,0,0)

__device__ __forceinline__ unsigned short f2bf(float f) {
    unsigned int u = __builtin_bit_cast(unsigned int, f);
    u = (u + 0x7fffu + ((u >> 16) & 1u)) >> 16;
    return (unsigned short)u;
}

__device__ __forceinline__ void gload_lds16(const void* g, void* l) {
    __builtin_amdgcn_global_load_lds(
        (const __attribute__((address_space(1))) void*)g,
        (__attribute__((address_space(3))) void*)l, 16, 0, 0);
}

template<int N> __device__ __forceinline__ void waitvm() {}  // N<0: no wait
template<> __device__ __forceinline__ void waitvm<6>() { asm volatile("s_waitcnt vmcnt(6)" ::: "memory"); }
template<> __device__ __forceinline__ void waitvm<0>() { asm volatile("s_waitcnt vmcnt(0)" ::: "memory"); }

// ---------- fp32 -> bf16 convert ----------
__global__ void cvt_f32_bf16(const float* __restrict__ in, unsigned short* __restrict__ out, long n) {
    long i = ((long)blockIdx.x * blockDim.x + threadIdx.x) * 8;
    long stride = (long)gridDim.x * blockDim.x * 8;
    for (; i < n; i += stride) {
        float4v v0 = *(const float4v*)(in + i);
        float4v v1 = *(const float4v*)(in + i + 4);
        u16x8 o;
        o[0] = f2bf(v0[0]); o[1] = f2bf(v0[1]); o[2] = f2bf(v0[2]); o[3] = f2bf(v0[3]);
        o[4] = f2bf(v1[0]); o[5] = f2bf(v1[1]); o[6] = f2bf(v1[2]); o[7] = f2bf(v1[3]);
        *(u16x8*)(out + i) = o;
    }
}

// ---------- GEMM1: z = H(bf16) @ VT(bf16)^T, 256x256 tile ----------
// m201-exact schedule: 8 phases per 2 K-tiles, stage issues 2/phase,
// vmcnt(6) only at end of P4 and P8. Register-carried b0/b1 frees LDS
// B-halves early, making in-place same-buffer restaging legal.
// Stage-slot map (iter i computes tiles 2i,2i+1; stages 2i+2,2i+3):
//   P1: Ah1(2i+1)  P2: Ah0(2i+2)  P3: Bh0(2i+2)  P4: Bh1(2i+2)
//   P5: Ah1(2i+2)  P6: Ah0(2i+3)  P7: Bh0(2i+3)  P8: Bh1(2i+3)
// Ledger (in-order vmem retirement): wait(6)@P4 retires through P1's issues;
// wait(6)@P8 retires through P5's. Every read-phase's data is covered:
//   P1 reads Ah0,Bh0(2i)   <- staged P2,P3(i-1), retired by P8(i-1)'s wait
//   P2 reads Bh1(2i)       <- P4(i-1), retired P8(i-1)
//   P3 reads Ah1(2i)       <- P5(i-1), retired P8(i-1) (exact margin)
//   P5 reads Ah0,Bh0(2i+1) <- P6,P7(i-1), retired P4(i)
//   P6 reads Bh1(2i+1)     <- P8(i-1), retired P4(i)
//   P7 reads Ah1(2i+1)     <- P1(i),   retired P4(i)
// Overwrite-safety: each stage targets a half last ds_read >=1 barrier-phase
// earlier (Bh* live in regs after their read phase).

#define STAGE_A(nA_, k0n, h, l) \
    gload_lds16(pA + ((l)*128 + (h)*64) * 4096L + (k0n), (nA_) + dA0 + ((l)*128 + (h)*64) * 64)
#define STAGE_B(nB_, k0n, h, l) \
    gload_lds16(pB + ((l)*128 + (h)*32) * 4096L + (k0n), (nB_) + dB0 + ((l)*128 + (h)*32) * 64)

#define LDA(sA_, QM) do { _Pragma("unroll") for (int mi = 0; mi < 4; ++mi) { \
    a[mi][0] = *(const bf16x8*)((sA_) + ((wr*128 + (QM)*64 + mi*16 + lan15) << 6) + g0); \
    a[mi][1] = *(const bf16x8*)((sA_) + ((wr*128 + (QM)*64 + mi*16 + lan15) << 6) + (g0 ^ 32)); } } while (0)
#define LDB(dst_, sB_, QN) do { _Pragma("unroll") for (int ni = 0; ni < 2; ++ni) { \
    dst_[ni][0] = *(const bf16x8*)((sB_) + ((wc*64 + (QN)*32 + ni*16 + lan15) << 6) + g0); \
    dst_[ni][1] = *(const bf16x8*)((sB_) + ((wc*64 + (QN)*32 + ni*16 + lan15) << 6) + (g0 ^ 32)); } } while (0)

#define DOMFMA(QM, QN, bset_) do { __builtin_amdgcn_s_setprio(1); \
    _Pragma("unroll") for (int mi = 0; mi < 4; ++mi) \
      _Pragma("unroll") for (int ni = 0; ni < 2; ++ni) { \
        acc[(QM)*4+mi][(QN)*2+ni] = MFMA16(a[mi][0], bset_[ni][0], acc[(QM)*4+mi][(QN)*2+ni]); \
        acc[(QM)*4+mi][(QN)*2+ni] = MFMA16(a[mi][1], bset_[ni][1], acc[(QM)*4+mi][(QN)*2+ni]); } \
    __builtin_amdgcn_s_setprio(0); } while (0)

#define BAR1() do { __builtin_amdgcn_s_barrier(); \
    asm volatile("s_waitcnt lgkmcnt(0)" ::: "memory"); \
    __builtin_amdgcn_sched_barrier(0); } while (0)
#define BAR2() do { __builtin_amdgcn_s_barrier(); \
    __builtin_amdgcn_sched_barrier(0); } while (0)

// One iteration: compute K-tiles in bA0/bB0 then bA1/bB1; stage per slot map.
#define ITER8(K1, K2, K3, S2, S3, V4, V8) do { \
  /*P1*/ LDA(bA0, 0); LDB(b0, bB0, 0); \
         STAGE_A(bA1, K1, 1, 0); STAGE_A(bA1, K1, 1, 1); \
         BAR1(); DOMFMA(0, 0, b0); BAR2(); \
  /*P2*/ LDB(b1, bB0, 1); \
         if (S2) { STAGE_A(bA0, K2, 0, 0); STAGE_A(bA0, K2, 0, 1); } \
         BAR1(); DOMFMA(0, 1, b1); BAR2(); \
  /*P3*/ LDA(bA0, 1); \
         if (S2) { STAGE_B(bB0, K2, 0, 0); STAGE_B(bB0, K2, 0, 1); } \
         BAR1(); DOMFMA(1, 1, b1); BAR2(); \
  /*P4*/ if (S2) { STAGE_B(bB0, K2, 1, 0); STAGE_B(bB0, K2, 1, 1); } \
         BAR1(); DOMFMA(1, 0, b0); waitvm<V4>(); BAR2(); \
  /*P5*/ LDA(bA1, 0); LDB(b0, bB1, 0); \
         if (S2) { STAGE_A(bA0, K2, 1, 0); STAGE_A(bA0, K2, 1, 1); } \
         BAR1(); DOMFMA(0, 0, b0); BAR2(); \
  /*P6*/ LDB(b1, bB1, 1); \
         if (S3) { STAGE_A(bA1, K3, 0, 0); STAGE_A(bA1, K3, 0, 1); } \
         BAR1(); DOMFMA(0, 1, b1); BAR2(); \
  /*P7*/ LDA(bA1, 1); \
         if (S3) { STAGE_B(bB1, K3, 0, 0); STAGE_B(bB1, K3, 0, 1); } \
         BAR1(); DOMFMA(1, 1, b1); BAR2(); \
  /*P8*/ if (S3) { STAGE_B(bB1, K3, 1, 0); STAGE_B(bB1, K3, 1, 1); } \
         BAR1(); DOMFMA(1, 0, b0); waitvm<V8>(); BAR2(); \
} while (0)

__global__ __launch_bounds__(512, 2) void gemm1_8ph(const unsigned short* __restrict__ A,  // [16384][4096]
                                                    const unsigned short* __restrict__ B,  // [2048][4096]
                                                    unsigned short* __restrict__ Z) {      // [16384][2048]
    __shared__ __align__(16) unsigned short lds[65536];   // 128 KiB

    const int tid   = threadIdx.x;
    const int lane  = tid & 63;
    const int wid   = tid >> 6;
    const int wr    = wid >> 2;          // 0..1
    const int wc    = wid & 3;           // 0..3
    const int lan15 = lane & 15;
    const int g0    = (((lane >> 4) ^ (lane & 7)) << 3);

    const int  bid = blockIdx.x;
    const long m0  = (long)(bid >> 3) * 256;
    const long n0  = (long)(bid & 7) * 256;

    const int q8    = tid >> 3;
    const int granA = (((tid & 7) ^ (q8 & 7)) << 3);
    const unsigned short* pA = A + (m0 + q8) * 4096L + granA;
    const int rB0   = (q8 & 31) + ((q8 >> 5) << 6);
    const unsigned short* pB = B + (n0 + rB0) * 4096L + granA;
    const int dA0   = (wid * 8) * 64;
    const int dB0   = ((wid & 3) * 8 + ((wid >> 2) << 6)) * 64;

    f32x4 acc[8][4] = {};
    bf16x8 a[4][2], b0[2][2], b1[2][2];

    unsigned short* bA0 = lds;
    unsigned short* bB0 = lds + 16384;
    unsigned short* bA1 = lds + 32768;
    unsigned short* bB1 = lds + 49152;

    // ---- prologue: t0 {Ah0,Bh0,Bh1,Ah1}, t1 {Ah0,Bh0,Bh1} = 14 issues ----
    STAGE_A(bA0, 0, 0, 0);  STAGE_A(bA0, 0, 0, 1);    // t0 Ah0
    STAGE_B(bB0, 0, 0, 0);  STAGE_B(bB0, 0, 0, 1);    // t0 Bh0
    STAGE_B(bB0, 0, 1, 0);  STAGE_B(bB0, 0, 1, 1);    // t0 Bh1
    STAGE_A(bA0, 0, 1, 0);  STAGE_A(bA0, 0, 1, 1);    // t0 Ah1
    STAGE_A(bA1, 64, 0, 0); STAGE_A(bA1, 64, 0, 1);   // t1 Ah0
    STAGE_B(bB1, 64, 0, 0); STAGE_B(bB1, 64, 0, 1);   // t1 Bh0
    STAGE_B(bB1, 64, 1, 0); STAGE_B(bB1, 64, 1, 1);   // t1 Bh1
    waitvm<6>();            // retires t0's 8 issues exactly
    BAR2();

    // ---- main loop: iters 0..30 (tiles 0..61 computed, 2..63 staged) ----
    for (int i = 0; i < 31; ++i) {
        ITER8((2 * i + 1) * 64, (2 * i + 2) * 64, (2 * i + 3) * 64, true, true, 6, 6);
    }
    // ---- final iter (tiles 62,63): stage only P1's Ah1(63); drain at P4 ----
    ITER8(63 * 64, 0, 0, false, false, 0, -1);

    // ---- epilogue: z bf16 store; C/D col = lane&15 (n), row = (lane>>4)*4+j ----
    const int rq = (lane >> 4) << 2;
    #pragma unroll
    for (int mi = 0; mi < 8; ++mi) {
        #pragma unroll
        for (int ni = 0; ni < 4; ++ni) {
            const long mb  = m0 + wr * 128 + mi * 16 + rq;
            const long nb2 = n0 + wc * 64 + ni * 16 + lan15;
            #pragma unroll
            for (int j = 0; j < 4; ++j)
                Z[(mb + j) * 2048L + nb2] = f2bf(acc[mi][ni][j]);
        }
    }
}

// ---------- GEMM2: grouped up-projection (write-BW floor, unchanged) ----------
#define U_PAD 80

__global__ __launch_bounds__(256) void gemm2(const unsigned short* __restrict__ Z,  // [16384][2048] bf16
                                             const float* __restrict__ U,           // [32][128][64] f32
                                             float* __restrict__ out) {             // [16384][4096] f32
    __shared__ __align__(16) unsigned short lU[128 * U_PAD];

    const int tid  = threadIdx.x;
    const int lane = tid & 63;
    const int wid  = tid >> 6;
    const int g    = blockIdx.x & 31;
    const long m0  = (long)(blockIdx.x >> 5) * 64;

    const float* ug = U + (long)g * (128 * 64);
    for (int i = tid; i < (128 * 64) / 4; i += 256) {
        const int r = i >> 4;
        const int c = (i << 2) & 63;
        float4v v = *(const float4v*)(ug + i * 4);
        unsigned short* d = &lU[r * U_PAD + c];
        d[0] = f2bf(v[0]); d[1] = f2bf(v[1]); d[2] = f2bf(v[2]); d[3] = f2bf(v[3]);
    }
    __syncthreads();

    const long mrow = m0 + wid * 16 + (lane & 15);
    const unsigned short* zrow = Z + mrow * 2048L + g * 64 + ((lane >> 4) << 3);
    const bf16x8 a0 = *(const bf16x8*)(zrow);
    const bf16x8 a1 = *(const bf16x8*)(zrow + 32);

    f32x4 acc[8] = {};
    const int blds = (lane & 15);
    const int kofs = (lane >> 4) << 3;
    #pragma unroll
    for (int ni = 0; ni < 8; ++ni) {
        const bf16x8 c0 = *(const bf16x8*)&lU[(ni * 16 + blds) * U_PAD + kofs];
        const bf16x8 c1 = *(const bf16x8*)&lU[(ni * 16 + blds) * U_PAD + 32 + kofs];
        acc[ni] = MFMA16(a0, c0, acc[ni]);
        acc[ni] = MFMA16(a1, c1, acc[ni]);
    }

    const long mb = m0 + wid * 16 + ((lane >> 4) << 2);
    const long cb = (long)g * 128 + (lane & 15);
    #pragma unroll
    for (int ni = 0; ni < 8; ++ni)
        #pragma unroll
        for (int j = 0; j < 4; ++j)
            out[(mb + j) * 4096L + cb + ni * 16] = acc[ni][j];
}

// ---------- launch ----------
extern "C" void kernel_launch(void* const* d_in, const int* in_sizes, int n_in,
                              void* d_out, int out_size, void* d_ws, size_t ws_size,
                              hipStream_t stream) {
    const float* hs = (const float*)d_in[0];   // [4,4096,4096] fp32
    const float* vt = (const float*)d_in[1];   // [2048,4096]   fp32
    const float* uw = (const float*)d_in[2];   // [32,128,64]   fp32
    float* out = (float*)d_out;

    unsigned short* hs_bf = (unsigned short*)d_ws;            // 67108864 bf16
    unsigned short* vt_bf = hs_bf + 67108864L;                //  8388608 bf16
    unsigned short* z_bf  = vt_bf + 8388608L;                 // 33554432 bf16

    cvt_f32_bf16<<<2048, 256, 0, stream>>>(hs, hs_bf, 67108864L);
    cvt_f32_bf16<<<512, 256, 0, stream>>>(vt, vt_bf, 8388608L);

    // GEMM1: (16384/256) x (2048/256) = 64 x 8 = 512 blocks, 512 threads
    gemm1_8ph<<<512, 512, 0, stream>>>(hs_bf, vt_bf, z_bf);

    // GEMM2: (16384/64) x 32 groups = 8192 blocks
    gemm2<<<8192, 256, 0, stream>>>(z_bf, uw, out);
}